// Round 2
// baseline (332.584 us; speedup 1.0000x reference)
//
#include <hip/hip_runtime.h>
#include <math.h>

#define NROWS 1000
#define NCOLS 78
// 2 * RADIUS * NUM_POINTS = 2*15*72
#define TWO_R_N 2160.0f

__device__ __forceinline__ float wsum(float v){
#pragma unroll
  for(int o=32;o;o>>=1) v += __shfl_xor(v,o,64);
  return v;
}
__device__ __forceinline__ float wmaxr(float v){
#pragma unroll
  for(int o=32;o;o>>=1) v = fmaxf(v, __shfl_xor(v,o,64));
  return v;
}
__device__ __forceinline__ unsigned long long wminu(unsigned long long v){
#pragma unroll
  for(int o=32;o;o>>=1){ unsigned long long u = __shfl_xor(v,o,64); v = (u<v)?u:v; }
  return v;
}

__global__ __launch_bounds__(256) void clr_task(const float* __restrict__ feat,
                                                const float* __restrict__ lab,
                                                float* __restrict__ ws)
{
  // b = blockIdx & 63 so the 16 tasks of one batch share an XCD (blockIdx%8)
  const int b = blockIdx.x & 63;
  const int l = blockIdx.x >> 6;
  const int task = b*16 + l;
  const float* __restrict__ F = feat + (size_t)b*NROWS*NCOLS;
  const float* __restrict__ P = lab + ((size_t)b*16 + (size_t)l)*NCOLS;

  __shared__ float sS[NROWS];    // sum |f[i,6:]-p[6:]|
  __shared__ float sC0[NROWS];   // f[i,0]
  __shared__ float sC1[NROWS];   // f[i,1]
  __shared__ float sRT[NROWS];   // r_i * t_i
  __shared__ float sCost[NROWS];
  __shared__ float sP[NCOLS];
  __shared__ float red[32];
  __shared__ unsigned long long redU[4];
  __shared__ int selIdx[64];
  __shared__ float bc[8];
  __shared__ int sK;

  const int tid = threadIdx.x;
  const int wave = tid >> 6, lane = tid & 63;

  if (tid < NCOLS) sP[tid] = P[tid];
  __syncthreads();

  // ---- Pass 1: wave-per-row scan of feature ----
  float accR=0.f, accT=0.f, accD=0.f, accL=0.f;
  const float p3=sP[3], p4=sP[4], p5=sP[5];
  for (int i = wave; i < NROWS; i += 4){
    const float* row = F + i*NCOLS;
    float a = fabsf(row[6+lane] - sP[6+lane]);   // cols 6..69
    float ev = 0.f;
    if (lane < 8)        a += fabsf(row[70+lane] - sP[70+lane]); // cols 70..77
    else if (lane < 16)  ev = row[lane-8];                       // cols 0..7
    float S = wsum(a);
    float c0 = __shfl(ev, 8, 64);
    float c1 = __shfl(ev, 9, 64);
    float f3 = __shfl(ev, 11, 64);
    float f4 = __shfl(ev, 12, 64);
    float f5 = __shfl(ev, 13, 64);
    if (lane == 0){
      float dr3=f3-p3, dr4=f4-p4;
      float r2 = dr3*dr3 + dr4*dr4;
      float t  = f5 - p5;
      sS[i]=S; sC0[i]=c0; sC1[i]=c1;
      sRT[i] = sqrtf(r2)*t;
      accR += r2; accT += t*t;
      float dd = S*(1.f/72.f);
      accD += dd*dd;
      accL += 1.f - (TWO_R_N - S)/(TWO_R_N + S + 1e-9f);
    }
  }
  if (lane==0){ red[wave*4+0]=accR; red[wave*4+1]=accT; red[wave*4+2]=accD; red[wave*4+3]=accL; }
  __syncthreads();
  if (tid==0){
    float R=0,T=0,D=0,L=0;
    for(int w=0;w<4;w++){R+=red[w*4];T+=red[w*4+1];D+=red[w*4+2];L+=red[w*4+3];}
    float Nr=fmaxf(sqrtf(R),1e-12f), Nt=fmaxf(sqrtf(T),1e-12f), Nd=fmaxf(sqrtf(D),1e-12f);
    bc[0] = 1.f/(Nr*Nt*Nd);
    int k = (int)L; if(k<1)k=1; if(k>64)k=64;   // trunc-toward-zero == astype(int32)
    sK = k;
  }
  // ---- column-wise log-softmax over the 1000 axis: max then sum-exp ----
  float m0=-INFINITY, m1=-INFINITY;
  for(int i=tid;i<NROWS;i+=256){ m0=fmaxf(m0,sC0[i]); m1=fmaxf(m1,sC1[i]); }
  m0=wmaxr(m0); m1=wmaxr(m1);
  if(lane==0){ red[16+wave]=m0; red[20+wave]=m1; }
  __syncthreads();
  if(tid==0){
    float M0=red[16],M1=red[20];
    for(int w=1;w<4;w++){M0=fmaxf(M0,red[16+w]); M1=fmaxf(M1,red[20+w]);}
    bc[1]=M0; bc[2]=M1;
  }
  __syncthreads();
  {
    float M0=bc[1], M1=bc[2];
    float s0=0.f, s1=0.f;
    for(int i=tid;i<NROWS;i+=256){ s0+=expf(sC0[i]-M0); s1+=expf(sC1[i]-M1); }
    s0=wsum(s0); s1=wsum(s1);
    if(lane==0){ red[16+wave]=s0; red[20+wave]=s1; }
    __syncthreads();
    if(tid==0){
      float S0=0,S1=0;
      for(int w=0;w<4;w++){S0+=red[16+w]; S1+=red[20+w];}
      bc[3]=M0+logf(S0); bc[4]=M1+logf(S1);
    }
  }
  __syncthreads();

  // ---- Pass 2: per-row cost ----
  {
    const float inv = bc[0], lse0=bc[3], lse1=bc[4];
    const float p0=sP[0], p1=sP[1];
    for(int i=tid;i<NROWS;i+=256){
      float ls0=sC0[i]-lse0, ls1=sC1[i]-lse1;
      float e0=expf(ls0), e1=expf(ls1);
      float focal=(1.f-e0)*(1.f-e0)*ls0*p0 + (1.f-e1)*(1.f-e1)*ls1*p1;
      float prod = sRT[i]*(sS[i]*(1.f/72.f))*inv;
      sCost[i] = 3.f*prod*prod + focal;
    }
  }
  __syncthreads();

  // ---- Top-k (k smallest costs, ties -> lowest index, like lax.top_k) ----
  const int k = sK;
  for(int it=0; it<k; ++it){
    unsigned long long best=~0ull;
    for(int i=tid;i<NROWS;i+=256){
      unsigned int u = __float_as_uint(sCost[i]);
      u = (u & 0x80000000u) ? ~u : (u | 0x80000000u);  // monotone float->uint
      unsigned long long key=((unsigned long long)u<<32)|(unsigned int)i;
      best = key<best?key:best;
    }
    best = wminu(best);
    if(lane==0) redU[wave]=best;
    __syncthreads();
    if(tid==0){
      unsigned long long bb=redU[0];
      for(int w=1;w<4;w++) bb = redU[w]<bb?redU[w]:bb;
      int idx=(int)(bb & 0xFFFFFFFFu);
      selIdx[it]=idx;
      sCost[idx]=INFINITY;
    }
    __syncthreads();
  }

  // ---- Phase C: losses over the k selected rows (wave 0 only) ----
  if (wave==0){
    bool act = lane < k;
    int idx = selIdx[act?lane:0];
    const float* row = F + idx*NCOLS;
    float g0=row[0],g1=row[1],g2=row[2],g3=row[3],g4=row[4],g5=row[5];
    float S = sS[idx];
    float m = act?1.f:0.f;
    float n2=wsum(g2*g2*m), n3=wsum(g3*g3*m), n4=wsum(g4*g4*m), n5=wsum(g5*g5*m);
    float l2=sP[2],l3=sP[3],l4=sP[4],l5=sP[5];
    float de2=fmaxf(sqrtf(n2+l2*l2),1e-12f);
    float de3=fmaxf(sqrtf(n3+l3*l3),1e-12f);
    float de4=fmaxf(sqrtf(n4+l4*l4),1e-12f);
    float de5=fmaxf(sqrtf(n5+l5*l5),1e-12f);
    float d2=g2/de2-l2/de2, d3=g3/de3-l3/de3, d4=g4/de4-l4/de4, d5=g5/de5-l5/de5;
    auto h=[](float d){ float ad=fabsf(d); return ad<1.f ? 0.5f*d*d : ad-0.5f; };
    float sl1 = 0.25f*(h(d2)+h(d3)+h(d4)+h(d5));
    const float p0=sP[0], p1=sP[1];
    float mm=fmaxf(g0,g1);
    float lsee=mm+logf(expf(g0-mm)+expf(g1-mm));
    float logpt=((p1>p0)?g1:g0)-lsee;   // tgt = argmax(prior[:2]), first-max -> 0
    float pt=expf(logpt);
    float fl=-(1.f-pt)*(1.f-pt)*logpt;
    float ll=1.f-(TWO_R_N - S)/(TWO_R_N + S + 1e-9f);
    float ssl=wsum(sl1*m), sll=wsum(ll*m), sfl=wsum(fl*m);
    if(lane==0){
      float invk=1.f/(float)k;
      float* o = ws + (size_t)task*3;
      o[0]=ssl*invk; o[1]=sll*invk; o[2]=sfl*invk;
    }
  }
}

__global__ __launch_bounds__(256) void clr_finalize(const float* __restrict__ ws,
                                                    float* __restrict__ out)
{
  float a=0.f, bsum=0.f, c=0.f;
  for(int i=threadIdx.x;i<1024;i+=256){
    a    += ws[i*3+0];
    bsum += ws[i*3+1];
    c    += ws[i*3+2];
  }
  a=wsum(a); bsum=wsum(bsum); c=wsum(c);
  __shared__ float r[12];
  int wave=threadIdx.x>>6, lane=threadIdx.x&63;
  if(lane==0){ r[wave*3]=a; r[wave*3+1]=bsum; r[wave*3+2]=c; }
  __syncthreads();
  if(threadIdx.x==0){
    float sa=0,sb=0,sc=0;
    for(int w=0;w<4;w++){sa+=r[w*3];sb+=r[w*3+1];sc+=r[w*3+2];}
    float sl1l=sa*(1.f/1024.f), ll=sb*(1.f/1024.f), fl=sc*(1.f/1024.f);
    // LW_XYTL=0.5, LW_LIOU=2.0, LW_CLS=2.0  (NOT W_CLS=1.0 — that's the cost weight)
    float loss = (sl1l>0.f ? 0.5f*sl1l : 0.f)
               + (ll  >0.f ? 2.0f*ll   : 0.f)
               + (fl  >0.f ? 2.0f*fl   : 0.f);
    out[0]=loss;
  }
}

extern "C" void kernel_launch(void* const* d_in, const int* in_sizes, int n_in,
                              void* d_out, int out_size, void* d_ws, size_t ws_size,
                              hipStream_t stream)
{
  const float* feat = (const float*)d_in[0];   // (64,1000,78) f32
  const float* lab  = (const float*)d_in[1];   // (64,16,78)  f32
  float* ws  = (float*)d_ws;                   // 1024*3 floats
  float* out = (float*)d_out;
  hipLaunchKernelGGL(clr_task, dim3(1024), dim3(256), 0, stream, feat, lab, ws);
  hipLaunchKernelGGL(clr_finalize, dim3(1), dim3(256), 0, stream, ws, out);
}

// Round 3
// 160.849 us; speedup vs baseline: 2.0677x; 2.0677x over previous
//
#include <hip/hip_runtime.h>
#include <math.h>

#define NROWS 1000
#define NCOLS 78
#define CH 64
#define CHF (CH*NCOLS)      // 4992 floats per chunk
#define CHF4 (CHF/4)        // 1248 float4
#define TWO_R_N 2160.0f     // 2*RADIUS*NUM_POINTS

typedef unsigned int uint;

__device__ __forceinline__ float wsum(float v){
#pragma unroll
  for(int o=32;o;o>>=1) v += __shfl_xor(v,o,64);
  return v;
}
__device__ __forceinline__ float wmaxr(float v){
#pragma unroll
  for(int o=32;o;o>>=1) v = fmaxf(v, __shfl_xor(v,o,64));
  return v;
}

__global__ void clr_init(float* ws){
  if (threadIdx.x < 4) ws[threadIdx.x] = 0.0f;  // [0..2] sums, [3] ticket (bits 0)
}

__global__ __launch_bounds__(256, 4) void clr_task(const float* __restrict__ feat,
                                                   const float* __restrict__ lab,
                                                   float* __restrict__ ws,
                                                   float* __restrict__ out)
{
  // b = blockIdx&63: the 16 tasks of one batch land on the same XCD (blockIdx%8)
  const int b = blockIdx.x & 63;
  const int l = blockIdx.x >> 6;
  const float* __restrict__ F = feat + (size_t)b*NROWS*NCOLS;
  const float* __restrict__ P = lab + ((size_t)b*16 + (size_t)l)*NCOLS;

  __shared__ __align__(16) float chunkbuf[CHF];  // 19968 B; reused: keys[1000], bins at +1024
  __shared__ float sS[NROWS], sC0[NROWS], sC1[NROWS], sRT[NROWS];
  __shared__ float sP[NCOLS];
  __shared__ float red[32];
  __shared__ float bc[6];
  __shared__ int sK;
  __shared__ uint rstate[2];
  __shared__ int selIdx[64];
  __shared__ int scount;

  const int tid = threadIdx.x;
  const int wave = tid >> 6, lane = tid & 63;

  if (tid < NCOLS) sP[tid] = P[tid];

  // ---- Pass 1: chunked stage + thread-quad-per-row ----
  float accR=0.f, accT=0.f, accD=0.f, accL=0.f;
  const int m = tid >> 2, q = tid & 3;
  for (int c = 0; c < 16; ++c){
    const int base = (c == 15) ? 936 : c*64;
    const int mlo  = (c == 15) ? 24 : 0;
    // stage 64 rows, coalesced float4 (base*NCOLS*4 bytes is 16B-aligned for all bases)
    {
      const float4* src4 = (const float4*)(F + base*NCOLS);
      float4* dst4 = (float4*)chunkbuf;
#pragma unroll
      for (int j = 0; j < 5; ++j){
        int e = tid + j*256;
        if (e < CHF4) dst4[e] = src4[e];
      }
    }
    __syncthreads();
    if (m >= mlo){
      const int r = base + m;
      const float* rowp = chunkbuf + m*NCOLS;
      float part = 0.f;
#pragma unroll
      for (int j = 0; j < 18; ++j){
        const int cc = 6 + q + 4*j;
        part += fabsf(rowp[cc] - sP[cc]);
      }
      float s1 = part + __shfl_xor(part, 1, 64);
      float S  = s1   + __shfl_xor(s1,   2, 64);
      if (q == 0){
        float c0 = rowp[0], c1 = rowp[1];
        float dr3 = rowp[3]-sP[3], dr4 = rowp[4]-sP[4];
        float r2 = dr3*dr3 + dr4*dr4;
        float t  = rowp[5]-sP[5];
        sS[r] = S; sC0[r] = c0; sC1[r] = c1;
        sRT[r] = sqrtf(r2)*t;
        accR += r2; accT += t*t;
        float dd = S*(1.f/72.f);
        accD += dd*dd;
        accL += 1.f - (TWO_R_N - S)/(TWO_R_N + S + 1e-9f);
      }
    }
    __syncthreads();
  }

  // ---- Block reductions: R,T,D,L + column max ----
  {
    float vR=wsum(accR), vT=wsum(accT), vD=wsum(accD), vL=wsum(accL);
    if (lane==0){ red[wave*4+0]=vR; red[wave*4+1]=vT; red[wave*4+2]=vD; red[wave*4+3]=vL; }
    float m0=-INFINITY, m1=-INFINITY;
    for(int i=tid;i<NROWS;i+=256){ m0=fmaxf(m0,sC0[i]); m1=fmaxf(m1,sC1[i]); }
    m0=wmaxr(m0); m1=wmaxr(m1);
    if (lane==0){ red[16+wave]=m0; red[20+wave]=m1; }
  }
  __syncthreads();
  if (tid==0){
    float R=0,T=0,D=0,L=0;
    for(int w=0;w<4;w++){R+=red[w*4];T+=red[w*4+1];D+=red[w*4+2];L+=red[w*4+3];}
    float Nr=fmaxf(sqrtf(R),1e-12f), Nt=fmaxf(sqrtf(T),1e-12f), Nd=fmaxf(sqrtf(D),1e-12f);
    bc[0] = 1.f/(Nr*Nt*Nd);
    int k = (int)L; if(k<1)k=1; if(k>64)k=64;   // trunc == astype(int32)
    sK = k;
    float M0=red[16],M1=red[20];
    for(int w=1;w<4;w++){M0=fmaxf(M0,red[16+w]); M1=fmaxf(M1,red[20+w]);}
    bc[1]=M0; bc[2]=M1;
    rstate[0]=0u; rstate[1]=(uint)k;
    scount=0;
  }
  __syncthreads();
  {
    float M0=bc[1], M1=bc[2];
    float s0=0.f, s1=0.f;
    for(int i=tid;i<NROWS;i+=256){ s0+=expf(sC0[i]-M0); s1+=expf(sC1[i]-M1); }
    s0=wsum(s0); s1=wsum(s1);
    if (lane==0){ red[16+wave]=s0; red[20+wave]=s1; }
  }
  __syncthreads();
  if (tid==0){
    float S0=0,S1=0;
    for(int w=0;w<4;w++){S0+=red[16+w]; S1+=red[20+w];}
    bc[3]=bc[1]+logf(S0); bc[4]=bc[2]+logf(S1);
  }
  __syncthreads();

  // ---- Pass 2: per-row cost -> monotone uint key ----
  uint* sKey = (uint*)chunkbuf;
  uint* bins = (uint*)(chunkbuf + 1024);
  {
    const float inv=bc[0], lse0=bc[3], lse1=bc[4];
    const float p0=sP[0], p1=sP[1];
    for(int i=tid;i<NROWS;i+=256){
      float ls0=sC0[i]-lse0, ls1=sC1[i]-lse1;
      float e0=expf(ls0), e1=expf(ls1);
      float focal=(1.f-e0)*(1.f-e0)*ls0*p0 + (1.f-e1)*(1.f-e1)*ls1*p1;
      float prod=sRT[i]*(sS[i]*(1.f/72.f))*inv;
      float cost=3.f*prod*prod+focal;
      uint x=__float_as_uint(cost);
      sKey[i] = (x & 0x80000000u) ? ~x : (x | 0x80000000u);
    }
  }
  __syncthreads();

  // ---- Radix select: T = k-th smallest key, rr = rank within equals ----
  for (int pass=0; pass<4; ++pass){
    const int shift = 24 - 8*pass;
    bins[tid] = 0u;
    __syncthreads();
    const uint hi = rstate[0];
    const uint maskhi = (pass==0) ? 0u : (0xFFFFFFFFu << (shift+8));
    for(int i=tid;i<NROWS;i+=256){
      uint u = sKey[i];
      if ((u & maskhi) == hi) atomicAdd(&bins[(u>>shift)&255u], 1u);
    }
    __syncthreads();
    if (wave==0){
      uint4 bv = ((uint4*)bins)[lane];
      uint local = bv.x+bv.y+bv.z+bv.w;
      uint cum = local;
#pragma unroll
      for(int d=1; d<64; d<<=1){ uint t=(uint)__shfl_up((int)cum,d,64); if(lane>=d) cum+=t; }
      const uint r = rstate[1];
      unsigned long long bal = __ballot(cum >= r);
      int sel = __ffsll((long long)bal) - 1;
      if (lane == sel){
        uint cacc = cum - local;
        uint arr[4]={bv.x,bv.y,bv.z,bv.w};
        uint v=0;
#pragma unroll
        for(int j=0;j<4;j++){
          if (cacc + arr[j] >= r){ v = (uint)(lane*4+j); break; }
          cacc += arr[j];
        }
        rstate[0] = hi | (v << shift);
        rstate[1] = r - cacc;
      }
    }
    __syncthreads();
  }

  // ---- Selection: all keys < T, plus rr lowest-indexed keys == T ----
  {
    const uint T = rstate[0];
    for(int i=tid;i<NROWS;i+=256){
      if (sKey[i] < T){ int p=atomicAdd(&scount,1); selIdx[p]=i; }
    }
    __syncthreads();
    if (wave==0){
      int need = (int)rstate[1];
      for(int bb=0; bb<NROWS && need>0; bb+=64){
        int i = bb + lane;
        bool pr = (i < NROWS) && (sKey[i] == T);
        unsigned long long msk = __ballot(pr);
        int below = __popcll(msk & ((1ull<<lane)-1ull));
        if (pr && below < need){ int p=atomicAdd(&scount,1); selIdx[p]=i; }
        int total = __popcll(msk);
        need -= (total < need ? total : need);
      }
    }
    __syncthreads();
  }

  // ---- Phase C: losses over selected rows (wave 0), fused finalize ----
  if (wave==0){
    const int k = sK;
    bool act = lane < k;
    int idx = selIdx[act?lane:0];
    const float* row = F + idx*NCOLS;
    float g0=row[0],g1=row[1],g2=row[2],g3=row[3],g4=row[4],g5=row[5];
    float S = sS[idx];
    float mk = act?1.f:0.f;
    float n2=wsum(g2*g2*mk), n3=wsum(g3*g3*mk), n4=wsum(g4*g4*mk), n5=wsum(g5*g5*mk);
    float l2=sP[2],l3=sP[3],l4=sP[4],l5=sP[5];
    float de2=fmaxf(sqrtf(n2+l2*l2),1e-12f);
    float de3=fmaxf(sqrtf(n3+l3*l3),1e-12f);
    float de4=fmaxf(sqrtf(n4+l4*l4),1e-12f);
    float de5=fmaxf(sqrtf(n5+l5*l5),1e-12f);
    float d2=g2/de2-l2/de2, d3=g3/de3-l3/de3, d4=g4/de4-l4/de4, d5=g5/de5-l5/de5;
    auto h=[](float d){ float ad=fabsf(d); return ad<1.f ? 0.5f*d*d : ad-0.5f; };
    float sl1 = 0.25f*(h(d2)+h(d3)+h(d4)+h(d5));
    const float p0=sP[0], p1=sP[1];
    float mm=fmaxf(g0,g1);
    float lsee=mm+logf(expf(g0-mm)+expf(g1-mm));
    float logpt=((p1>p0)?g1:g0)-lsee;   // tgt=argmax(prior[:2]), first-max -> 0
    float pt=expf(logpt);
    float fl=-(1.f-pt)*(1.f-pt)*logpt;
    float ll=1.f-(TWO_R_N - S)/(TWO_R_N + S + 1e-9f);
    float ssl=wsum(sl1*mk), sll=wsum(ll*mk), sfl=wsum(fl*mk);
    if (lane==0){
      float invk=1.f/(float)k;
      atomicAdd(ws+0, ssl*invk);
      atomicAdd(ws+1, sll*invk);
      atomicAdd(ws+2, sfl*invk);
      __threadfence();
      int told = atomicAdd((int*)ws + 3, 1);
      if (told == (int)gridDim.x - 1){
        // all blocks' sum-adds precede their ticket add; read via atomic RMW
        float sa = atomicAdd(ws+0, 0.0f);
        float sb = atomicAdd(ws+1, 0.0f);
        float sc = atomicAdd(ws+2, 0.0f);
        float sl1l = sa*(1.f/1024.f), llm = sb*(1.f/1024.f), flm = sc*(1.f/1024.f);
        // LW_XYTL=0.5, LW_LIOU=2.0, LW_CLS=2.0
        float loss = (sl1l>0.f ? 0.5f*sl1l : 0.f)
                   + (llm >0.f ? 2.0f*llm  : 0.f)
                   + (flm >0.f ? 2.0f*flm  : 0.f);
        out[0]=loss;
      }
    }
  }
}

extern "C" void kernel_launch(void* const* d_in, const int* in_sizes, int n_in,
                              void* d_out, int out_size, void* d_ws, size_t ws_size,
                              hipStream_t stream)
{
  const float* feat = (const float*)d_in[0];   // (64,1000,78) f32
  const float* lab  = (const float*)d_in[1];   // (64,16,78)  f32
  float* ws  = (float*)d_ws;                   // [0..2] float sums, [3] int ticket
  float* out = (float*)d_out;
  hipLaunchKernelGGL(clr_init, dim3(1), dim3(64), 0, stream, ws);
  hipLaunchKernelGGL(clr_task, dim3(1024), dim3(256), 0, stream, feat, lab, ws, out);
}

// Round 4
// 146.447 us; speedup vs baseline: 2.2710x; 1.0983x over previous
//
#include <hip/hip_runtime.h>
#include <math.h>

#define NROWS 1000
#define TWO_R_N 2160.0f   // 2*RADIUS*NUM_POINTS
typedef unsigned int uint;

__device__ __forceinline__ float wsum(float v){
#pragma unroll
  for(int o=32;o;o>>=1) v += __shfl_xor(v,o,64);
  return v;
}
__device__ __forceinline__ float wmaxr(float v){
#pragma unroll
  for(int o=32;o;o>>=1) v = fmaxf(v, __shfl_xor(v,o,64));
  return v;
}

__global__ void clr_init(float* ws){
  if (threadIdx.x < 4) ws[threadIdx.x] = 0.0f;  // [0..2] sums, [3] ticket
}

__global__ __launch_bounds__(256,4) void clr_task(const float* __restrict__ feat,
                                                  const float* __restrict__ lab,
                                                  float* __restrict__ ws,
                                                  float* __restrict__ out)
{
  // b = blockIdx&63: 16 tasks of one batch land on one XCD (blockIdx%8) -> F stays L2-resident
  const int b = blockIdx.x & 63;
  const int l = blockIdx.x >> 6;
  const float* __restrict__ F = feat + (size_t)b*NROWS*78;
  const float* __restrict__ P = lab + ((size_t)b*16 + (size_t)l)*78;

  __shared__ __align__(16) float4 sRow[NROWS];  // (S, rt, c0, c1) per row; 16 KB
  __shared__ float redf[32];
  __shared__ uint  redu[224];                   // [0..191] search counts, [208..223] eq counts
  __shared__ float bc[6];
  __shared__ int sK;
  __shared__ int selIdx[64];
  __shared__ int scount;

  const int tid = threadIdx.x, wave = tid>>6, lane = tid&63;
  const int m = tid>>2, q = tid&3;

  // Prior columns into registers (uniform addresses -> L1 broadcast). No LDS, no barrier.
  const float2* P2 = (const float2*)P;
  float2 pv[9];
#pragma unroll
  for(int j=0;j<9;j++) pv[j] = P2[3+q+4*j];     // float cols {6+2q+8j, +1}
  const float2 p01 = P2[0], p23 = P2[1], p45 = P2[2];

  // ---- Pass 1: quad-per-row, direct global float2 reads, barrier-free ----
  float accR=0.f, accT=0.f, accD=0.f, accL=0.f;
  for(int c=0;c<16;++c){
    int r = c*64 + m;                 // quad-uniform predicate -> shfl safe
    if (r < NROWS){
      const float2* R2 = (const float2*)(F + (size_t)r*78);
      float2 rv[9];
#pragma unroll
      for(int j=0;j<9;j++) rv[j] = R2[3+q+4*j];
      float part = 0.f;
#pragma unroll
      for(int j=0;j<9;j++) part += fabsf(rv[j].x-pv[j].x) + fabsf(rv[j].y-pv[j].y);
      float s1 = part + __shfl_xor(part,1,64);
      float S  = s1   + __shfl_xor(s1,  2,64);
      if (q==0){
        float2 c01=R2[0], c23=R2[1], c45=R2[2];
        float dr3=c23.y-p23.y, dr4=c45.x-p45.x;
        float r2 = dr3*dr3 + dr4*dr4;
        float t  = c45.y-p45.y;
        sRow[r] = make_float4(S, sqrtf(r2)*t, c01.x, c01.y);
        accR += r2; accT += t*t;
        float dd = S*(1.f/72.f); accD += dd*dd;
        accL += 1.f - (TWO_R_N - S)/(TWO_R_N + S + 1e-9f);
      }
    }
  }

  // ---- Block reductions ----
  {
    float vR=wsum(accR), vT=wsum(accT), vD=wsum(accD), vL=wsum(accL);
    if(lane==0){ redf[wave*4]=vR; redf[wave*4+1]=vT; redf[wave*4+2]=vD; redf[wave*4+3]=vL; }
  }
  __syncthreads();                                   // #1: publishes sRow + redf
  if(tid==0){
    float R=0,T=0,D=0,L=0;
    for(int w=0;w<4;w++){R+=redf[w*4];T+=redf[w*4+1];D+=redf[w*4+2];L+=redf[w*4+3];}
    float Nr=fmaxf(sqrtf(R),1e-12f), Nt=fmaxf(sqrtf(T),1e-12f), Nd=fmaxf(sqrtf(D),1e-12f);
    bc[0] = 1.f/(Nr*Nt*Nd);
    int k=(int)L; if(k<1)k=1; if(k>64)k=64;          // trunc == astype(int32)
    sK = k; scount = 0;
  }
  // column-wise softmax over 1000 axis: max
  {
    float m0=-INFINITY, m1=-INFINITY;
    for(int i=tid;i<NROWS;i+=256){ float4 v=sRow[i]; m0=fmaxf(m0,v.z); m1=fmaxf(m1,v.w); }
    m0=wmaxr(m0); m1=wmaxr(m1);
    if(lane==0){ redf[16+wave]=m0; redf[20+wave]=m1; }
  }
  __syncthreads();                                   // #2
  if(tid==0){
    float M0=redf[16],M1=redf[20];
    for(int w=1;w<4;w++){M0=fmaxf(M0,redf[16+w]); M1=fmaxf(M1,redf[20+w]);}
    bc[1]=M0; bc[2]=M1;
  }
  __syncthreads();                                   // #3
  {
    float M0=bc[1], M1=bc[2], s0=0.f, s1=0.f;
    for(int i=tid;i<NROWS;i+=256){ float4 v=sRow[i]; s0+=expf(v.z-M0); s1+=expf(v.w-M1); }
    s0=wsum(s0); s1=wsum(s1);
    if(lane==0){ redf[24+wave]=s0; redf[28+wave]=s1; }
  }
  __syncthreads();                                   // #4
  if(tid==0){
    float S0=0,S1=0;
    for(int w=0;w<4;w++){S0+=redf[24+w]; S1+=redf[28+w];}
    bc[3]=bc[1]+logf(S0); bc[4]=bc[2]+logf(S1);
  }
  __syncthreads();                                   // #5

  // ---- Pass 2: per-row cost -> monotone uint keys, in registers ----
  uint key[4]; int rowid[4];
  {
    const float inv=bc[0], lse0=bc[3], lse1=bc[4];
    const float p0=p01.x, p1=p01.y;
#pragma unroll
    for(int j=0;j<4;j++){
      int i = tid + 256*j; rowid[j]=i;
      uint kk = 0xFFFFFFFFu;                         // phantom: sorts above all real keys
      if(i<NROWS){
        float4 v = sRow[i];
        float ls0=v.z-lse0, ls1=v.w-lse1;
        float e0=expf(ls0), e1=expf(ls1);
        float focal=(1.f-e0)*(1.f-e0)*ls0*p0 + (1.f-e1)*(1.f-e1)*ls1*p1;
        float prod=v.y*(v.x*(1.f/72.f))*inv;
        float cost=3.f*prod*prod+focal;
        uint x=__float_as_uint(cost);
        kk=(x&0x80000000u)?~x:(x|0x80000000u);
      }
      key[j]=kk;
    }
  }

  // ---- k-th smallest via 2-bit MSB-first binary search (ballot counts, no atomics) ----
  uint pref=0u, r=(uint)sK;
  for(int it=0; it<16; ++it){
    const int shift = 30 - 2*it;
    const uint maskhi = (it==0) ? 0u : (0xFFFFFFFFu << (shift+2));
    int c0=0,c1=0,c2=0;
#pragma unroll
    for(int j=0;j<4;j++){
      bool mt = ((key[j]^pref)&maskhi)==0u;
      uint bb = (key[j]>>shift)&3u;
      c0 += __popcll(__ballot(mt && bb==0u));
      c1 += __popcll(__ballot(mt && bb==1u));
      c2 += __popcll(__ballot(mt && bb==2u));
    }
    if(lane==0){ uint* s=&redu[it*12+wave*3]; s[0]=(uint)c0; s[1]=(uint)c1; s[2]=(uint)c2; }
    __syncthreads();                                 // #6..#21
    uint C0=0,C1=0,C2=0;
    for(int w=0;w<4;w++){ C0+=redu[it*12+w*3]; C1+=redu[it*12+w*3+1]; C2+=redu[it*12+w*3+2]; }
    uint bits;
    if(r<=C0)            bits=0u;
    else if(r<=C0+C1)    {bits=1u; r-=C0;}
    else if(r<=C0+C1+C2) {bits=2u; r-=C0+C1;}
    else                 {bits=3u; r-=C0+C1+C2;}
    pref |= bits<<shift;
  }
  const uint T=pref, rr=r;   // select all < T plus first rr (by row index) == T

  // ---- Selection ----
#pragma unroll
  for(int j=0;j<4;j++){
    if(key[j]<T){ int p=atomicAdd(&scount,1); selIdx[p]=rowid[j]; }
  }
  unsigned long long emk[4];
#pragma unroll
  for(int j=0;j<4;j++){
    emk[j]=__ballot(key[j]==T);
    if(lane==0) redu[208+j*4+wave]=(uint)__popcll(emk[j]);
  }
  __syncthreads();                                   // #22
  {
    uint pre[4]; uint run=0;
    for(int j=0;j<4;j++){
      for(int w=0;w<4;w++){
        if(w==wave) pre[j]=run;
        run += redu[208+j*4+w];
      }
    }
#pragma unroll
    for(int j=0;j<4;j++){
      if(key[j]==T){
        uint below=(uint)__popcll(emk[j] & ((1ull<<lane)-1ull));
        if(pre[j]+below < rr){ int p=atomicAdd(&scount,1); selIdx[p]=rowid[j]; }
      }
    }
  }
  __syncthreads();                                   // #23

  // ---- Phase C: losses over selected rows (wave 0), fused global finalize ----
  if (wave==0){
    const int k=sK;
    bool act = lane < k;
    int idx = selIdx[act?lane:0];
    const float2* R2=(const float2*)(F + (size_t)idx*78);
    float2 g01=R2[0], g23=R2[1], g45=R2[2];
    float S = sRow[idx].x;
    float mk = act?1.f:0.f;
    float n2=wsum(g23.x*g23.x*mk), n3=wsum(g23.y*g23.y*mk);
    float n4=wsum(g45.x*g45.x*mk), n5=wsum(g45.y*g45.y*mk);
    float l2=p23.x, l3=p23.y, l4=p45.x, l5=p45.y;
    float de2=fmaxf(sqrtf(n2+l2*l2),1e-12f);
    float de3=fmaxf(sqrtf(n3+l3*l3),1e-12f);
    float de4=fmaxf(sqrtf(n4+l4*l4),1e-12f);
    float de5=fmaxf(sqrtf(n5+l5*l5),1e-12f);
    float d2=g23.x/de2-l2/de2, d3=g23.y/de3-l3/de3, d4=g45.x/de4-l4/de4, d5=g45.y/de5-l5/de5;
    auto h=[](float d){ float ad=fabsf(d); return ad<1.f ? 0.5f*d*d : ad-0.5f; };
    float sl1 = 0.25f*(h(d2)+h(d3)+h(d4)+h(d5));
    float p0=p01.x, p1=p01.y;
    float mm=fmaxf(g01.x,g01.y);
    float lsee=mm+logf(expf(g01.x-mm)+expf(g01.y-mm));
    float logpt=((p1>p0)?g01.y:g01.x)-lsee;   // tgt=argmax(prior[:2]), first-max -> 0
    float pt=expf(logpt);
    float fl=-(1.f-pt)*(1.f-pt)*logpt;
    float ll=1.f-(TWO_R_N - S)/(TWO_R_N + S + 1e-9f);
    float ssl=wsum(sl1*mk), sll=wsum(ll*mk), sfl=wsum(fl*mk);
    if(lane==0){
      float invk=1.f/(float)k;
      atomicAdd(ws+0, ssl*invk);
      atomicAdd(ws+1, sll*invk);
      atomicAdd(ws+2, sfl*invk);
      __threadfence();
      int told = atomicAdd((int*)ws + 3, 1);
      if (told == (int)gridDim.x - 1){
        float sa = atomicAdd(ws+0, 0.0f);
        float sb = atomicAdd(ws+1, 0.0f);
        float sc = atomicAdd(ws+2, 0.0f);
        float sl1l = sa*(1.f/1024.f), llm = sb*(1.f/1024.f), flm = sc*(1.f/1024.f);
        // LW_XYTL=0.5, LW_LIOU=2.0, LW_CLS=2.0
        float loss = (sl1l>0.f ? 0.5f*sl1l : 0.f)
                   + (llm >0.f ? 2.0f*llm  : 0.f)
                   + (flm >0.f ? 2.0f*flm  : 0.f);
        out[0]=loss;
      }
    }
  }
}

extern "C" void kernel_launch(void* const* d_in, const int* in_sizes, int n_in,
                              void* d_out, int out_size, void* d_ws, size_t ws_size,
                              hipStream_t stream)
{
  const float* feat = (const float*)d_in[0];   // (64,1000,78) f32
  const float* lab  = (const float*)d_in[1];   // (64,16,78)  f32
  float* ws  = (float*)d_ws;
  float* out = (float*)d_out;
  hipLaunchKernelGGL(clr_init, dim3(1), dim3(64), 0, stream, ws);
  hipLaunchKernelGGL(clr_task, dim3(1024), dim3(256), 0, stream, feat, lab, ws, out);
}